// Round 2
// baseline (248.026 us; speedup 1.0000x reference)
//
#include <hip/hip_runtime.h>

#define HW (512 * 1024)          // 524288 = 2^19
#define NPIX (4 * HW)            // 2097152
#define NCLS 19
#define NB 256                   // lovasz histogram buckets over [0,8)
#define BSCALE 32.0f             // NB / 8.0 : bucket width 1/32
#define L2E 1.4426950408889634f
#define LN2 0.6931471805599453f

#define NTHR 512
#define NBLK 512
#define ITERS 4                  // pixels/thread = 2*ITERS = 8 ; pixels/block = 4096

// acc layout (doubles): 0 ce, 1 focal, 2..20 inter[19], 21..39 sumP[19],
//                       40..58 cnt[19], 59 lovasz_sum
#define ACC_BYTES 512
#define HIST_ENTRIES (NCLS * NB)

// ---------------- K1: everything streaming, one pass over logits ----------------
__global__ __launch_bounds__(NTHR) void k_main(const float* __restrict__ lg,
                                               const int* __restrict__ masks,
                                               unsigned* __restrict__ gHist,
                                               double* __restrict__ acc) {
    __shared__ unsigned hist[HIST_ENTRIES];     // packed: low16 total, high16 bg
    __shared__ float sInter[NCLS];
    __shared__ unsigned sCnt[NCLS];
    __shared__ float sSumP[NCLS];
    __shared__ float sCE, sFocal;
    int tid = threadIdx.x;
    for (int k = tid; k < HIST_ENTRIES; k += NTHR) hist[k] = 0u;
    if (tid < NCLS) { sInter[tid] = 0.f; sCnt[tid] = 0u; sSumP[tid] = 0.f; }
    if (tid == 0) { sCE = 0.f; sFocal = 0.f; }
    __syncthreads();

    float sumP[NCLS];
#pragma unroll
    for (int c = 0; c < NCLS; ++c) sumP[c] = 0.f;
    float ceAcc = 0.f, foAcc = 0.f;

    int base2 = blockIdx.x * (NTHR * ITERS);    // float2-granular pixel index base
    for (int it = 0; it < ITERS; ++it) {
        int i2 = base2 + it * NTHR + tid;
        int pix = i2 * 2;
        int b = pix >> 19;
        int hw = pix & (HW - 1);
        const float* lp = lg + (((size_t)(b * NCLS)) << 19) + hw;
        int2 tt = *reinterpret_cast<const int2*>(masks + pix);
        int t0 = tt.x, t1 = tt.y;

        float2 l[NCLS];
        float m0 = -1e30f, m1 = -1e30f;
#pragma unroll
        for (int c = 0; c < NCLS; ++c) {
            l[c] = *reinterpret_cast<const float2*>(lp + (((size_t)c) << 19));
            m0 = fmaxf(m0, l[c].x);
            m1 = fmaxf(m1, l[c].y);
        }

        float lt0 = 0.f, lt1 = 0.f;          // raw target logits
        float S0 = 0.f, S1 = 0.f;
        float pu0 = 0.f, pu1 = 0.f;          // unnormalized target probs
#pragma unroll
        for (int c = 0; c < NCLS; ++c) {
            float x0 = l[c].x, x1 = l[c].y;
            bool f0 = (c == t0), f1 = (c == t1);
            // lovasz error histogram (uses RAW logit, before overwrite)
            float e0 = f0 ? (1.f - x0) : (1.f + x0);
            float e1 = f1 ? (1.f - x1) : (1.f + x1);
            if (e0 > 0.f) {
                int k = (int)(e0 * BSCALE);
                k = (k < NB) ? k : (NB - 1);
                atomicAdd(&hist[c * NB + k], f0 ? 1u : 0x10001u);
            }
            if (e1 > 0.f) {
                int k = (int)(e1 * BSCALE);
                k = (k < NB) ? k : (NB - 1);
                atomicAdd(&hist[c * NB + k], f1 ? 1u : 0x10001u);
            }
            if (f0) lt0 = x0;
            if (f1) lt1 = x1;
            float p0 = exp2f((x0 - m0) * L2E);
            float p1 = exp2f((x1 - m1) * L2E);
            S0 += p0; S1 += p1;
            if (f0) pu0 = p0;
            if (f1) pu1 = p1;
            l[c].x = p0; l[c].y = p1;        // reuse as unnormalized probs
        }

        float inv0 = 1.f / S0, inv1 = 1.f / S1;
#pragma unroll
        for (int c = 0; c < NCLS; ++c) sumP[c] += l[c].x * inv0 + l[c].y * inv1;

        float logpt0 = (lt0 - m0) - log2f(S0) * LN2;
        float logpt1 = (lt1 - m1) - log2f(S1) * LN2;
        float pt0 = pu0 * inv0, pt1 = pu1 * inv1;
        ceAcc -= logpt0 + logpt1;
        float om0 = 1.f - pt0, om1 = 1.f - pt1;
        foAcc -= 0.25f * (om0 * om0 * logpt0 + om1 * om1 * logpt1);
        atomicAdd(&sInter[t0], pt0);
        atomicAdd(&sInter[t1], pt1);
        atomicAdd(&sCnt[t0], 1u);
        atomicAdd(&sCnt[t1], 1u);
    }

    // wave-level reduction before LDS accumulation
    int lane = tid & 63;
#pragma unroll
    for (int c = 0; c < NCLS; ++c) {
        float v = sumP[c];
#pragma unroll
        for (int s = 32; s > 0; s >>= 1) v += __shfl_xor(v, s);
        if (lane == 0) atomicAdd(&sSumP[c], v);
    }
    {
        float v = ceAcc, w = foAcc;
#pragma unroll
        for (int s = 32; s > 0; s >>= 1) { v += __shfl_xor(v, s); w += __shfl_xor(w, s); }
        if (lane == 0) { atomicAdd(&sCE, v); atomicAdd(&sFocal, w); }
    }
    __syncthreads();

    // flush histogram (packed u32; no per-bucket overflow: block<=4096/bucket,
    // global per class-bucket peak ~26K < 65536)
    for (int k = tid; k < HIST_ENTRIES; k += NTHR) {
        unsigned v = hist[k];
        if (v) atomicAdd(&gHist[k], v);
    }
    if (tid < NCLS) {
        atomicAdd(&acc[2 + tid], (double)sInter[tid]);
        atomicAdd(&acc[21 + tid], (double)sSumP[tid]);
        atomicAdd(&acc[40 + tid], (double)sCnt[tid]);
    }
    if (tid == 0) {
        atomicAdd(&acc[0], (double)sCE);
        atomicAdd(&acc[1], (double)sFocal);
    }
}

// ---------------- K2: per-class suffix scan over 256 buckets -> lovasz ----------------
__global__ __launch_bounds__(NB) void k_scan(const unsigned* __restrict__ gHist,
                                             double* __restrict__ acc) {
    int c = blockIdx.x;
    int tid = threadIdx.x;
    unsigned v = gHist[c * NB + tid];
    double all = (double)(v & 0xFFFFu);
    double bg = (double)(v >> 16);
    double P = acc[40 + c];

    __shared__ double sN[NB];
    __shared__ double sB[NB];
    __shared__ double red[NB];
    sN[tid] = all;
    sB[tid] = bg;
    __syncthreads();

    // Hillis-Steele inclusive suffix scan (higher bucket = higher error = earlier in sort)
    for (int s = 1; s < NB; s <<= 1) {
        double tn = (tid + s < NB) ? sN[tid + s] : 0.0;
        double tb = (tid + s < NB) ? sB[tid + s] : 0.0;
        __syncthreads();
        sN[tid] += tn;
        sB[tid] += tb;
        __syncthreads();
    }
    double n = sN[tid] - all;   // counts strictly above this bucket
    double B = sB[tid] - bg;

    double contrib = 0.0;
    if (P > 0.5 && all > 0.0) {
        double Gend = (n + all) / (P + B + bg);
        double Gstart = n / (P + B);
        double emid = ((double)tid + 0.5) / (double)BSCALE;
        contrib = emid * (Gend - Gstart);
    }
    red[tid] = contrib;
    __syncthreads();
    for (int s = NB / 2; s > 0; s >>= 1) {
        if (tid < s) red[tid] += red[tid + s];
        __syncthreads();
    }
    if (tid == 0) atomicAdd(&acc[59], red[0]);
}

// ---------------- K3: combine ----------------
__global__ void k_combine(const double* __restrict__ acc, float* __restrict__ outv) {
    if (threadIdx.x != 0) return;
    double ce = acc[0] / (double)NPIX;
    double fo = acc[1] / (double)NPIX;
    double dsum = 0.0, npres = 0.0;
    for (int c = 0; c < NCLS; ++c) {
        double cnt = acc[40 + c];
        if (cnt > 0.5) {
            double inter = acc[2 + c];
            double uni = acc[21 + c] + cnt;
            dsum += (2.0 * inter + 1e-8) / (uni + 1e-8);
            npres += 1.0;
        }
    }
    double dice = (npres > 0.0) ? (1.0 - dsum / npres) : 1.0;
    double lov = acc[59] / (double)NCLS;
    outv[0] = (float)(ce + fo + dice + 0.5 * lov);
}

extern "C" void kernel_launch(void* const* d_in, const int* in_sizes, int n_in,
                              void* d_out, int out_size, void* d_ws, size_t ws_size,
                              hipStream_t stream) {
    const float* lg = (const float*)d_in[0];
    const int* masks = (const int*)d_in[1];
    float* outv = (float*)d_out;

    char* ws = (char*)d_ws;
    double* acc = (double*)ws;                       // 512 B
    unsigned* gHist = (unsigned*)(ws + ACC_BYTES);   // 19*256*4 = 19456 B

    hipMemsetAsync(d_ws, 0, ACC_BYTES + HIST_ENTRIES * 4, stream);

    k_main<<<NBLK, NTHR, 0, stream>>>(lg, masks, gHist, acc);
    k_scan<<<NCLS, NB, 0, stream>>>(gHist, acc);
    k_combine<<<1, 64, 0, stream>>>(acc, outv);
}